// Round 9
// baseline (402.482 us; speedup 1.0000x reference)
//
#include <hip/hip_runtime.h>

// Problem: B=32, C=2048, Q=128, E=200. Inputs fp32, OUTPUT fp32 (B,C,4E).
// Ledger: R6 cooperative hang (retired). R7 swizzle: FETCH 82->55MB, dur flat
//   (L2-latency theory falsified; swizzle kept). R8 manual 2-deep pipeline:
//   FLAT (compiler already pipelines; ILP not binding). VALUBusy pinned ~49%
//   == 3 waves/SIMD covering ~200cyc L2 latency with ~32cyc FMA per step:
//   TLP-bound. R9: LDS 42.5->33.9 KB via chunked P (P_h[32][64], phase 3 in
//   two q-halves, merged e-column passes) -> 4 blocks/CU, traffic unchanged,
//   summation order unchanged. +2 barriers.
#define B_ 32
#define C_ 2048
#define Q_ 128
#define E_ 200
#define TB 32

typedef __attribute__((ext_vector_type(4))) float f32x4;

// ---------------------------------------------------------------- K0: prep
// blocks 0..895:    xqT[b][e][q] = xq[b][q][e] via padded-LDS 32x32 tile
// blocks 896..1919: s_q[b,q] = dot(xq[b,q,:], w2), one wave per q-row
__global__ __launch_bounds__(256) void prep_kernel(const float* __restrict__ xq,
                                                   const float* __restrict__ w,
                                                   float* __restrict__ xqT,
                                                   float* __restrict__ sq) {
    __shared__ float tl[32][33];
    if (blockIdx.x < 896) {
        const int blk = blockIdx.x;               // B * 4 * 7 = 896
        const int b  = blk / 28;
        const int r  = blk - b * 28;
        const int qt = r / 7, et = r - (r / 7) * 7;
        const int q0 = qt * 32, e0 = et * 32;
        const int tx = threadIdx.x & 31, ty = threadIdx.x >> 5;   // 32 x 8
        #pragma unroll
        for (int i = 0; i < 4; ++i) {
            const int q = q0 + ty + 8 * i, e = e0 + tx;
            if (e < E_) tl[ty + 8 * i][tx] = xq[((size_t)b * Q_ + q) * E_ + e];
        }
        __syncthreads();
        #pragma unroll
        for (int i = 0; i < 4; ++i) {
            const int e = e0 + ty + 8 * i, q = q0 + tx;
            if (e < E_) xqT[((size_t)b * E_ + e) * Q_ + q] = tl[tx][ty + 8 * i];
        }
    } else {
        const int wave = (blockIdx.x - 896) * 4 + (threadIdx.x >> 6);  // 0..B*Q-1
        const int lane = threadIdx.x & 63;
        const float* row = xq + (size_t)wave * E_;
        float a = 0.f;
        if (lane < 50) {                                    // 50*4 = 200 = E_
            const f32x4 v  = *(const f32x4*)&row[lane * 4];
            const f32x4 wv = *(const f32x4*)&w[E_ + lane * 4];
            a = (v.x * wv.x + v.y * wv.y) + (v.z * wv.z + v.w * wv.w);
        }
        #pragma unroll
        for (int off = 32; off; off >>= 1) a += __shfl_xor(a, off);
        if (lane == 0) sq[wave] = a;
    }
}

// ---------------------------------------------------------------- K2
// R7 row2 + chunked-P LDS (33.9 KB -> 4 blocks/CU). Swizzle kept.
__global__ __launch_bounds__(256) void row2_kernel(const float* __restrict__ xc_g,
                                                   const float* __restrict__ xq_g,
                                                   const float* __restrict__ xqT_g,
                                                   const float* __restrict__ w_g,
                                                   const float* __restrict__ sq_g,
                                                   float* __restrict__ m_g,
                                                   float* __restrict__ out) {
    __shared__ float scw3_l[TB][E_];   // 25.6 KB  (xc*w3)
    __shared__ float P_h[TB][64];      //  8.0 KB  (half of P at a time)
    __shared__ float sc_l[TB];

    const int t    = threadIdx.x;
    // XCD swizzle (bijective, 2048 blocks): all 64 tiles of one b on one XCD.
    const int blk  = blockIdx.x;
    const int x    = blk & 7;
    const int g    = blk >> 3;               // 0..255
    const int b    = x * 4 + (g >> 6);
    const int tile = g & 63;
    const int bc0  = b * C_ + tile * TB;

    // ---- phase 0: stage scw3 rows; s_c = xc.w1 (8 lanes per row) ----
    {
        const int r  = t >> 3;               // 0..31
        const int k  = t & 7;                // 0..7
        const int e0 = k * 25;
        const float* xc_row = xc_g + (size_t)(bc0 + r) * E_;
        float p1 = 0.f;
        #pragma unroll
        for (int i = 0; i < 25; ++i) {
            const int e = e0 + i;
            const float v = xc_row[e];
            scw3_l[r][e] = v * w_g[2 * E_ + e];
            p1 = fmaf(v, w_g[e], p1);
        }
        p1 += __shfl_xor(p1, 1);
        p1 += __shfl_xor(p1, 2);
        p1 += __shfl_xor(p1, 4);
        if (k == 0) sc_l[r] = p1;
    }
    __syncthreads();                         // (A) scw3 + sc_l visible

    const int qg = t & 31;
    const int cg = t >> 5;                   // 0..7
    const int c4 = cg * 4;
    const int q4 = qg * 4;

    // ---- phase 1: S[4c][4q] = scw3_tile @ xqT  (xqT reads lane-coalesced) ----
    f32x4 acc[4] = {};
    const float* xqT_b = xqT_g + (size_t)b * E_ * Q_;
    for (int e = 0; e < E_; e += 4) {
        const f32x4 x0 = *(const f32x4*)&xqT_b[(e + 0) * Q_ + q4];
        const f32x4 x1 = *(const f32x4*)&xqT_b[(e + 1) * Q_ + q4];
        const f32x4 x2 = *(const f32x4*)&xqT_b[(e + 2) * Q_ + q4];
        const f32x4 x3 = *(const f32x4*)&xqT_b[(e + 3) * Q_ + q4];
        #pragma unroll
        for (int ci = 0; ci < 4; ++ci) {
            const f32x4 a = *(const f32x4*)&scw3_l[c4 + ci][e];  // broadcast: free
            acc[ci] += a.x * x0 + a.y * x1 + a.z * x2 + a.w * x3;
        }
    }

    // ---- phase 2: in-register softmax over q (reduce across the 32-lane q-group) ----
    const f32x4 sqv = *(const f32x4*)&sq_g[b * Q_ + q4];
    float mx[4], sm[4];
    #pragma unroll
    for (int ci = 0; ci < 4; ++ci) {
        acc[ci] += sc_l[c4 + ci] + sqv;
        mx[ci] = fmaxf(fmaxf(acc[ci].x, acc[ci].y), fmaxf(acc[ci].z, acc[ci].w));
    }
    #pragma unroll
    for (int off = 16; off; off >>= 1) {
        #pragma unroll
        for (int ci = 0; ci < 4; ++ci) mx[ci] = fmaxf(mx[ci], __shfl_xor(mx[ci], off));
    }
    if (qg == 0) {
        #pragma unroll
        for (int ci = 0; ci < 4; ++ci) m_g[bc0 + c4 + ci] = mx[ci];
    }
    #pragma unroll
    for (int ci = 0; ci < 4; ++ci) {
        f32x4 p;
        p.x = __expf(acc[ci].x - mx[ci]);
        p.y = __expf(acc[ci].y - mx[ci]);
        p.z = __expf(acc[ci].z - mx[ci]);
        p.w = __expf(acc[ci].w - mx[ci]);
        acc[ci] = p;
        sm[ci] = (p.x + p.y) + (p.z + p.w);
    }
    #pragma unroll
    for (int off = 16; off; off >>= 1) {
        #pragma unroll
        for (int ci = 0; ci < 4; ++ci) sm[ci] += __shfl_xor(sm[ci], off);
    }
    #pragma unroll
    for (int ci = 0; ci < 4; ++ci) acc[ci] *= (1.f / sm[ci]);   // normalized probs

    // ---- phase 3: c2q = P @ xq, P chunked through LDS in two q-halves.
    // Both e-columns (e4a, e4b) accumulated in one merged q-loop; per-output
    // summation order identical to R7 (ascending q, step 4, same FMA grouping).
    const float* xq_b = xq_g + (size_t)b * Q_ * E_;
    const int e4a = q4;                       // < 128 always
    const int e4b = 128 + q4;                 // active when < 200 (qg < 18)
    const bool act_b = (e4b < E_);
    f32x4 oa[4] = {}, ob[4] = {};

    // half 0: q = 0..63
    if (qg < 16) {
        #pragma unroll
        for (int ci = 0; ci < 4; ++ci) *(f32x4*)&P_h[c4 + ci][q4] = acc[ci];
    }
    __syncthreads();                         // (B1) P half-0 visible
    for (int q = 0; q < 64; q += 4) {
        const f32x4 v0 = *(const f32x4*)&xq_b[(q + 0) * E_ + e4a];
        const f32x4 v1 = *(const f32x4*)&xq_b[(q + 1) * E_ + e4a];
        const f32x4 v2 = *(const f32x4*)&xq_b[(q + 2) * E_ + e4a];
        const f32x4 v3 = *(const f32x4*)&xq_b[(q + 3) * E_ + e4a];
        f32x4 w0, w1, w2, w3;
        if (act_b) {
            w0 = *(const f32x4*)&xq_b[(q + 0) * E_ + e4b];
            w1 = *(const f32x4*)&xq_b[(q + 1) * E_ + e4b];
            w2 = *(const f32x4*)&xq_b[(q + 2) * E_ + e4b];
            w3 = *(const f32x4*)&xq_b[(q + 3) * E_ + e4b];
        }
        #pragma unroll
        for (int ci = 0; ci < 4; ++ci) {
            const f32x4 p = *(const f32x4*)&P_h[c4 + ci][q];     // broadcast
            oa[ci] += p.x * v0 + p.y * v1 + p.z * v2 + p.w * v3;
            if (act_b) ob[ci] += p.x * w0 + p.y * w1 + p.z * w2 + p.w * w3;
        }
    }
    __syncthreads();                         // (B2) half-0 reads done
    if (qg >= 16) {
        #pragma unroll
        for (int ci = 0; ci < 4; ++ci) *(f32x4*)&P_h[c4 + ci][q4 - 64] = acc[ci];
    }
    __syncthreads();                         // (B3) P half-1 visible
    for (int q = 64; q < Q_; q += 4) {
        const f32x4 v0 = *(const f32x4*)&xq_b[(q + 0) * E_ + e4a];
        const f32x4 v1 = *(const f32x4*)&xq_b[(q + 1) * E_ + e4a];
        const f32x4 v2 = *(const f32x4*)&xq_b[(q + 2) * E_ + e4a];
        const f32x4 v3 = *(const f32x4*)&xq_b[(q + 3) * E_ + e4a];
        f32x4 w0, w1, w2, w3;
        if (act_b) {
            w0 = *(const f32x4*)&xq_b[(q + 0) * E_ + e4b];
            w1 = *(const f32x4*)&xq_b[(q + 1) * E_ + e4b];
            w2 = *(const f32x4*)&xq_b[(q + 2) * E_ + e4b];
            w3 = *(const f32x4*)&xq_b[(q + 3) * E_ + e4b];
        }
        #pragma unroll
        for (int ci = 0; ci < 4; ++ci) {
            const f32x4 p = *(const f32x4*)&P_h[c4 + ci][q - 64];  // broadcast
            oa[ci] += p.x * v0 + p.y * v1 + p.z * v2 + p.w * v3;
            if (act_b) ob[ci] += p.x * w0 + p.y * w1 + p.z * w2 + p.w * w3;
        }
    }

    // ---- epilogue: output segments 0..3E for both column sets ----
    #pragma unroll
    for (int ci = 0; ci < 4; ++ci) {
        const size_t row = (size_t)(bc0 + c4 + ci);
        float* orow = out + row * (4 * E_);
        const f32x4 xa = *(const f32x4*)&xc_g[row * E_ + e4a];
        *(f32x4*)&orow[e4a]          = xa;
        *(f32x4*)&orow[E_ + e4a]     = oa[ci];
        *(f32x4*)&orow[2 * E_ + e4a] = xa * oa[ci];
        if (act_b) {
            const f32x4 xb = *(const f32x4*)&xc_g[row * E_ + e4b];
            *(f32x4*)&orow[e4b]          = xb;
            *(f32x4*)&orow[E_ + e4b]     = ob[ci];
            *(f32x4*)&orow[2 * E_ + e4b] = xb * ob[ci];
        }
    }
}

// ---------------------------------------------------------------- K3
// Fused stats + partial q2c. Each block: global per-b max M over m[b,:]
// (redundant, bitwise-identical across blocks), then its 64-c chunk:
//   part[blk][e] = sum_c exp(m[c]-M)*xc[c][e];  den[blk] = sum_c exp(m[c]-M)
__global__ __launch_bounds__(256) void q2c_partial(const float* __restrict__ xc_g,
                                                   const float* __restrict__ m_g,
                                                   float* __restrict__ part,
                                                   float* __restrict__ den) {
    __shared__ float redl[4];
    __shared__ float wl[64];
    const int blk = blockIdx.x;               // 0..B*32-1
    const int b = blk >> 5, g = blk & 31;     // 32 chunks of 64 c per b
    const int t = threadIdx.x;
    const int c0 = g * 64;

    // global max over m[b, 0:2048]
    float mx = -3.4e38f;
    #pragma unroll
    for (int j = 0; j < 8; ++j) mx = fmaxf(mx, m_g[b * C_ + t + j * 256]);
    #pragma unroll
    for (int off = 32; off; off >>= 1) mx = fmaxf(mx, __shfl_xor(mx, off));
    if ((t & 63) == 0) redl[t >> 6] = mx;
    __syncthreads();
    const float M = fmaxf(fmaxf(redl[0], redl[1]), fmaxf(redl[2], redl[3]));

    if (t < 64) {                              // wave 0: chunk weights
        const float e = __expf(m_g[b * C_ + c0 + t] - M);
        wl[t] = e;
        float s = e;
        #pragma unroll
        for (int off = 32; off; off >>= 1) s += __shfl_xor(s, off);
        if (t == 0) den[blk] = s;
    }
    __syncthreads();

    if (t < E_) {
        float acc = 0.f;
        const float* base = xc_g + ((size_t)(b * C_ + c0)) * E_ + t;
        #pragma unroll 8
        for (int c = 0; c < 64; ++c) acc = fmaf(wl[c], base[(size_t)c * E_], acc);
        part[(size_t)blk * E_ + t] = acc;
    }
}

// ---------------------------------------------------------------- K4
// Fused reduce + segment-3 write. Block = 64 c-rows of one b:
//   q2c[e] = (sum_g part[g][e]) / (sum_g den[g]);  out[...,3E:4E] = xc * q2c
__global__ __launch_bounds__(256) void out4_kernel(const float* __restrict__ xc_g,
                                                   const float* __restrict__ part,
                                                   const float* __restrict__ den,
                                                   float* __restrict__ out) {
    __shared__ float q2c_l[E_];
    __shared__ float invt;
    const int blk = blockIdx.x;               // 0..B*32-1
    const int b = blk >> 5, g = blk & 31;
    const int c0 = g * 64;
    const int t = threadIdx.x;

    if (t < E_) {
        float a = 0.f;
        #pragma unroll
        for (int gg = 0; gg < 32; ++gg) a += part[(size_t)(b * 32 + gg) * E_ + t];
        q2c_l[t] = a;
    }
    if (t >= 224) {                            // lanes 32..63 of wave 3
        float s = den[b * 32 + (t - 224)];
        #pragma unroll
        for (int off = 16; off; off >>= 1) s += __shfl_xor(s, off);
        if (t == 224) invt = 1.f / s;
    }
    __syncthreads();

    const float iv = invt;
    const int e4 = (t % 50) * 4;
    const int r0 = t / 50;                     // 0..3 (t<200), t>=200 idle
    if (t < 200) {
        #pragma unroll
        for (int kk = 0; kk < 16; ++kk) {
            const size_t row = (size_t)(b * C_ + c0 + kk * 4 + r0);
            const f32x4 xcv = *(const f32x4*)&xc_g[row * E_ + e4];
            const f32x4 qv  = *(const f32x4*)&q2c_l[e4];
            *(f32x4*)&out[row * (4 * E_) + 3 * E_ + e4] = xcv * (qv * iv);
        }
    }
}

extern "C" void kernel_launch(void* const* d_in, const int* in_sizes, int n_in,
                              void* d_out, int out_size, void* d_ws, size_t ws_size,
                              hipStream_t stream) {
    // order-robust input selection by element count
    const float* xc = (const float*)d_in[0];
    const float* xq = (const float*)d_in[1];
    const float* w  = (const float*)d_in[2];
    for (int i = 0; i < n_in; ++i) {
        if      (in_sizes[i] == B_ * C_ * E_) xc = (const float*)d_in[i];
        else if (in_sizes[i] == B_ * Q_ * E_) xq = (const float*)d_in[i];
        else if (in_sizes[i] == 3 * E_)       w  = (const float*)d_in[i];
    }
    float* out = (float*)d_out;

    float* ws    = (float*)d_ws;
    float* sq    = ws;                 // B*Q   = 4096
    float* m     = sq + B_ * Q_;       // B*C   = 65536
    float* xqT   = m + B_ * C_;        // B*E*Q = 819200  (~3.3 MB)
    // part/den alias xqT: written only AFTER row2's last xqT read (stream-ordered);
    // 1024*200 + 1024 = 205824 floats fits well inside xqT's 819200.
    float* part  = xqT;                            // [B*32][E_]
    float* den   = xqT + 1024 * E_;                // [B*32]

    prep_kernel <<<1920,               256, 0, stream>>>(xq, w, xqT, sq);
    row2_kernel <<<B_ * (C_ / TB),     256, 0, stream>>>(xc, xq, xqT, w, sq, m, out);
    q2c_partial <<<B_ * 32,            256, 0, stream>>>(xc, m, part, den);
    out4_kernel <<<B_ * 32,            256, 0, stream>>>(xc, part, den, out);
}